// Round 1
// baseline (172.636 us; speedup 1.0000x reference)
//
#include <hip/hip_runtime.h>
#include <stdint.h>

// Problem constants
#define IM_HW   16384            // 128*128 pixels
#define NBINS   33120            // 184*180
#define NMAPS   32               // b*c = 2*16
#define INV_NORM (1.0f / 128.0f)

#define BBITS   5                // bins per bucket = 32
#define NBUCK   1035             // NBINS/32 exactly
#define CAPB    4352             // slots/bucket (mean 3865, +7.8 sigma), %4==0
#define SLAB    192              // LDS slots per fine bin (mean 120.8, +6.5 sigma)
#define SSTR    194              // slab stride (even: b64-aligned; ≡2 mod 32: bank spread)
#define NB_SCAT 768              // scatter blocks (3 resident/CU for latency overlap)
#define NT_SCAT 512              // scatter threads/block
#define LDSVOT  5376             // >= ceil(4e6/768)+3 = 5212 block-local votes
#define OVR_CAP 8192             // overflow list capacity (votes)

// Weight encoding: top-13 bits of the f16 bit pattern, stored at [19,32).
__device__ __forceinline__ float w_from_top13(unsigned e) {   // e>>19 = top13
  const unsigned short hb = (unsigned short)((e >> 19) << 3);
  return (float)__builtin_bit_cast(_Float16, hb);
}
__device__ __forceinline__ float f16u(unsigned short h) {
  return (float)__builtin_bit_cast(_Float16, h);
}

// ---------- bucket scatter (R8-proven) + fused xT(f16) transpose prologue -----
// R9: 768x512 (was 256x1024). 1 block/CU left all phase latencies (LDS-atomic
// rank, global reservation, flush stores) exposed between barriers; 3 blocks/CU
// (33.9KB LDS each) co-schedule across phases.
__global__ __launch_bounds__(NT_SCAT) void k_scatter_bucket(
    const float* __restrict__ x, unsigned short* __restrict__ xT2,
    const int* __restrict__ vp, const int* __restrict__ vb,
    const float* __restrict__ vw, int nv,
    unsigned* __restrict__ globcur,      // [NBUCK] bucket fills (pre-zeroed)
    unsigned* __restrict__ ovrcnt,       // [1] overflow count (pre-zeroed)
    uint2*   __restrict__ ovrlist,       // [OVR_CAP]
    unsigned* __restrict__ sorted) {     // [NBUCK*CAPB] 4B entries
  __shared__ unsigned h[NBUCK];          // per-bucket counts
  __shared__ unsigned lstart[NBUCK];     // local exclusive starts
  __shared__ unsigned cur[NBUCK];        // global reserved bases
  __shared__ unsigned lds[LDSVOT];       // block-local bucket-sorted votes (21.5KB)

  const int tid = threadIdx.x;

  // fused transpose+cvt: x[32][16384] -> xT2[16384][32] f16 (write-coalesced)
  // 524288 elements on the first 512 blocks (1024 each); blocks >=512 skip.
  if (blockIdx.x < 512) {
    const int base = blockIdx.x * 1024;
    #pragma unroll
    for (int k = 0; k < 2; ++k) {
      const int i = base + k * NT_SCAT + tid;  // i = p*32 + m
      const int m = i & 31, p = i >> 5;
      xT2[i] = __builtin_bit_cast(unsigned short, (_Float16)x[m * IM_HW + p]);
    }
  }

  const int chunk = (((nv + NB_SCAT - 1) / NB_SCAT) + 3) & ~3;   // 4-aligned
  const int c0 = blockIdx.x * chunk;
  const int c1 = min(nv, c0 + chunk);
  const int cnt = (c1 > c0) ? (c1 - c0) : 0;    // <= 5212 <= LDSVOT

  for (int i = tid; i < NBUCK; i += NT_SCAT) h[i] = 0u;
  __syncthreads();

  // stage + rank (1 LDS atomic per vote; return value = within-bucket rank)
  unsigned e[16];
  unsigned short rr[16], bu16[16];
  const int ng = cnt >> 2;                       // groups of 4 votes (<=1303)
  const int4*   vp4 = (const int4*)(vp + c0);
  const int4*   vb4 = (const int4*)(vb + c0);
  const float4* vw4 = (const float4*)(vw + c0);
  #pragma unroll
  for (int j = 0; j < 4; ++j) {
    const int g = tid + j * NT_SCAT;
    if (g < ng) {
      const int4 p = vp4[g]; const int4 b = vb4[g]; const float4 w = vw4[g];
      const int k = j * 4;
      #define STAGE(q, PP, BB, WW) { \
        const unsigned short hw = __builtin_bit_cast(unsigned short, (_Float16)(WW)); \
        e[k + q] = (unsigned)(PP) | (((unsigned)(BB) & 31u) << 14) | (((unsigned)hw >> 3) << 19); \
        bu16[k + q] = (unsigned short)((unsigned)(BB) >> BBITS); \
        rr[k + q] = (unsigned short)atomicAdd(&h[(unsigned)(BB) >> BBITS], 1u); }
      STAGE(0, p.x, b.x, w.x) STAGE(1, p.y, b.y, w.y)
      STAGE(2, p.z, b.z, w.z) STAGE(3, p.w, b.w, w.w)
      #undef STAGE
    }
  }
  // robustness tail (cnt%4, zero for nv=4M): straight to overflow list
  const int tail0 = ng * 4;
  if (tid < cnt - tail0) {
    const int gi = c0 + tail0 + tid;
    unsigned o = atomicAdd(ovrcnt, 1u);
    if (o < OVR_CAP)
      ovrlist[o] = make_uint2((unsigned)vp[gi] | ((unsigned)vb[gi] << 14),
                              __float_as_uint(vw[gi]));
  }
  __syncthreads();

  // single-wave exclusive scan of h -> lstart (wave 0: 17 buckets/lane + shfl)
  if (tid < 64) {
    const int lo = tid * 17, hi = min(NBUCK, lo + 17);   // 64*17=1088 >= 1035
    unsigned s = 0;
    for (int i = lo; i < hi; ++i) s += h[i];
    unsigned inc = s;
    #pragma unroll
    for (int d = 1; d < 64; d <<= 1) {
      const unsigned v = __shfl_up(inc, d);
      if (tid >= d) inc += v;
    }
    unsigned run = inc - s;                               // exclusive base
    for (int i = lo; i < hi; ++i) { lstart[i] = run; run += h[i]; }
  }
  __syncthreads();
  // one global reservation per non-empty bucket
  for (int i = tid; i < NBUCK; i += NT_SCAT)
    cur[i] = (h[i] != 0u) ? atomicAdd(&globcur[i], h[i]) : 0u;
  __syncthreads();

  // place into LDS, bucket-clustered (plain b32 writes; rank from registers)
  #pragma unroll
  for (int j = 0; j < 4; ++j) {
    const int g = tid + j * NT_SCAT;
    if (g < ng) {
      #pragma unroll
      for (int q = 0; q < 4; ++q) {
        const int k = j * 4 + q;
        lds[lstart[bu16[k]] + (unsigned)rr[k]] = e[k];
      }
    }
  }
  __syncthreads();

  // flush: wave w -> buckets w, w+8, ...; contiguous LDS -> contiguous global
  const int wid = tid >> 6, lane = tid & 63;
  for (int bu = wid; bu < NBUCK; bu += 8) {
    const unsigned c = h[bu];
    if (c == 0u) continue;                       // wave-uniform branch
    const unsigned gb = cur[bu], lb = lstart[bu];
    for (unsigned s = lane; s < c; s += 64) {
      const unsigned E = lds[lb + s];
      const unsigned g = gb + s;
      if (g < CAPB) {
        sorted[(size_t)bu * CAPB + g] = E;
      } else {
        unsigned o = atomicAdd(ovrcnt, 1u);
        if (o < OVR_CAP) {
          const unsigned pp  = E & 0x3FFFu;
          const unsigned bin = ((unsigned)bu << BBITS) + ((E >> 14) & 31u);
          ovrlist[o] = make_uint2(pp | (bin << 14), __float_as_uint(w_from_top13(E)));
        }
      }
    }
  }
}

// ---------- per-bucket spmm + fused overflow merge + transposed epilogue ------
// R9 compute layout: 64 lanes = 8 vote-slots (q) x 8 map-QUADS (mp); one 8B
// gather (uint2 = 4 f16 maps) + 4 fma per vote-lane. Halves the replicated
// per-vote overhead (addr calc + w-decode) vs the 16-pair layout.
__global__ __launch_bounds__(512) void k_spmm_static(
    const unsigned* __restrict__ sorted, const unsigned* __restrict__ globcur,
    const unsigned short* __restrict__ xT2, float* __restrict__ out,
    unsigned* __restrict__ ovrcnt, uint2* __restrict__ ovrlist) {
  __shared__ unsigned sv[32 * SSTR];       // 24,832 B
  __shared__ unsigned cur[32];
  __shared__ float tile[32][33];           // [bin][map], +1 pad
  const int tid = threadIdx.x;
  const int bu = blockIdx.x;
  const int n = min((int)globcur[bu], CAPB);

  if (tid < 32) cur[tid] = 0u;
  __syncthreads();

  // place: 4 votes per 16B load, 1 LDS atomic + 1 b32 write per vote
  const uint4* src = (const uint4*)(sorted + (size_t)bu * CAPB);  // CAPB%4==0
  const int nq = n >> 2;
  #define PLACE(E) { \
    const unsigned fb = ((E) >> 14) & 31u; \
    const unsigned s = atomicAdd(&cur[fb], 1u); \
    if (s < SLAB) sv[fb * SSTR + s] = (E) & 0xFFF83FFFu; \
    else { \
      unsigned o = atomicAdd(ovrcnt, 1u); \
      if (o < OVR_CAP) \
        ovrlist[o] = make_uint2(((E) & 0x3FFFu) | ((((unsigned)bu << BBITS) + fb) << 14), \
                                __float_as_uint(w_from_top13(E))); } }
  for (int i = tid; i < nq; i += 512) {
    const uint4 q = src[i];
    PLACE(q.x) PLACE(q.y) PLACE(q.z) PLACE(q.w)
  }
  if (tid < (n & 3)) {                     // tail votes (<=3)
    const unsigned E = sorted[(size_t)bu * CAPB + (n & ~3) + tid];
    PLACE(E)
  }
  #undef PLACE
  __syncthreads();

  // compute: wave wv -> bins [wv*4, wv*4+4). Slot q takes votes 2q,2q+1 per
  // 16-vote iter (uint2 pairs); per vote one uint2 load = 4 f16 maps + 4 fma.
  #define WDEC(E) ((float)__builtin_bit_cast(_Float16, (unsigned short)((E) >> 16)))
  const uint2* xh4 = (const uint2*)xT2;    // [16384][8] map-quads
  const int wv = tid >> 6, lane = tid & 63;
  const int q = lane >> 3, mp = lane & 7;
  #pragma unroll
  for (int s4 = 0; s4 < 4; ++s4) {
    const int b = wv * 4 + s4;
    const int cnt = min((int)cur[b], SLAB);
    const unsigned* seg = &sv[b * SSTR];
    float a0 = 0.0f, a1 = 0.0f, a2 = 0.0f, a3 = 0.0f;
    int base = 0;
    for (; base + 16 <= cnt; base += 16) { // 16 votes/iter: slot q -> 2 votes
      const uint2 a = *(const uint2*)(seg + base + 2 * q);
      {
        const uint2 xv = xh4[(a.x & 0x3FFFu) * 8 + mp];
        const float w = WDEC(a.x);
        a0 += w * f16u((unsigned short)(xv.x & 0xFFFFu));
        a1 += w * f16u((unsigned short)(xv.x >> 16));
        a2 += w * f16u((unsigned short)(xv.y & 0xFFFFu));
        a3 += w * f16u((unsigned short)(xv.y >> 16));
      }
      {
        const uint2 xv = xh4[(a.y & 0x3FFFu) * 8 + mp];
        const float w = WDEC(a.y);
        a0 += w * f16u((unsigned short)(xv.x & 0xFFFFu));
        a1 += w * f16u((unsigned short)(xv.x >> 16));
        a2 += w * f16u((unsigned short)(xv.y & 0xFFFFu));
        a3 += w * f16u((unsigned short)(xv.y >> 16));
      }
    }
    for (int j = base + q; j < cnt; j += 8) {    // tail: <=15 votes, stride-8
      const unsigned E = seg[j];
      const uint2 xv = xh4[(E & 0x3FFFu) * 8 + mp];
      const float w = WDEC(E);
      a0 += w * f16u((unsigned short)(xv.x & 0xFFFFu));
      a1 += w * f16u((unsigned short)(xv.x >> 16));
      a2 += w * f16u((unsigned short)(xv.y & 0xFFFFu));
      a3 += w * f16u((unsigned short)(xv.y >> 16));
    }
    // combine the 8 slots (lanes mp, mp+8, ..., mp+56)
    a0 += __shfl_xor(a0, 8); a0 += __shfl_xor(a0, 16); a0 += __shfl_xor(a0, 32);
    a1 += __shfl_xor(a1, 8); a1 += __shfl_xor(a1, 16); a1 += __shfl_xor(a1, 32);
    a2 += __shfl_xor(a2, 8); a2 += __shfl_xor(a2, 16); a2 += __shfl_xor(a2, 32);
    a3 += __shfl_xor(a3, 8); a3 += __shfl_xor(a3, 16); a3 += __shfl_xor(a3, 32);
    if (lane < 8) {
      tile[b][4 * mp]     = a0 * INV_NORM;
      tile[b][4 * mp + 1] = a1 * INV_NORM;
      tile[b][4 * mp + 2] = a2 * INV_NORM;
      tile[b][4 * mp + 3] = a3 * INV_NORM;
    }
  }
  #undef WDEC
  __syncthreads();

  // fused overflow merge: rare entries for THIS bucket -> atomicAdd into tile
  {
    unsigned nov = *ovrcnt;
    nov = nov < (unsigned)OVR_CAP ? nov : (unsigned)OVR_CAP;
    if (nov) {
      for (unsigned idx = tid; idx < nov * 32u; idx += 512u) {
        const unsigned vi = idx >> 5, m2 = idx & 31u;
        const uint2 vv = ovrlist[vi];
        const unsigned bin = vv.x >> 14;
        if ((bin >> BBITS) == (unsigned)bu) {
          const float xv = f16u(xT2[(vv.x & 0x3FFFu) * 32 + m2]);
          atomicAdd(&tile[bin & 31u][m2],
                    __uint_as_float(vv.y) * xv * INV_NORM);
        }
      }
      __syncthreads();
    }
  }

  // fused transposed write: out[m][bin_base + c] for c in [0,32).
  {
    const int row  = tid >> 4;             // 0..31 (map index)
    const int col2 = (tid & 15) * 2;       // 0,2,..,30 (bin offset)
    const int gb0  = bu << BBITS;
    const float2 v2 = make_float2(tile[col2][row], tile[col2 + 1][row]);
    *(float2*)(out + (size_t)row * NBINS + gb0 + col2) = v2;
  }
}

// ---------- fallback (ws too small): R1 LDS-histogram version -----------------
__global__ __launch_bounds__(1024) void ht_fallback(const float* __restrict__ x,
                                                    const int* __restrict__ vp,
                                                    const int* __restrict__ vb,
                                                    const float* __restrict__ vw,
                                                    float* __restrict__ out, int nv) {
  __shared__ float hist[NBINS];
  for (int i = threadIdx.x; i < NBINS; i += 1024) hist[i] = 0.0f;
  __syncthreads();
  const int map = blockIdx.x >> 3, chunk = blockIdx.x & 7;
  const float* xm = x + map * IM_HW;
  const int per = (nv + 7) / 8;
  const int start = chunk * per, end = min(nv, start + per);
  for (int i = start + (int)threadIdx.x; i < end; i += 1024)
    atomicAdd(&hist[vb[i]], xm[vp[i]] * vw[i]);
  __syncthreads();
  float* om = out + map * NBINS;
  for (int i = threadIdx.x; i < NBINS; i += 1024)
    atomicAdd(&om[i], hist[i] * INV_NORM);
}

extern "C" void kernel_launch(void* const* d_in, const int* in_sizes, int n_in,
                              void* d_out, int out_size, void* d_ws, size_t ws_size,
                              hipStream_t stream) {
  const float* x  = (const float*)d_in[0];
  const int*   vp = (const int*)d_in[1];
  const int*   vb = (const int*)d_in[2];
  const float* vw = (const float*)d_in[3];
  float* out = (float*)d_out;
  const int nv = in_sizes[1];

  // ws layout (all sections 16B-aligned)
  char* w = (char*)d_ws;
  unsigned*       sorted  = (unsigned*)w;       w += (size_t)NBUCK * CAPB * 4; // 18.0 MB
  unsigned short* xT2     = (unsigned short*)w; w += (size_t)IM_HW * NMAPS * 2; // 1 MB
  uint2*          ovrlist = (uint2*)w;          w += (size_t)OVR_CAP * 8;      // 64 KB
  unsigned*       globcur = (unsigned*)w;       w += (size_t)NBUCK * 4;        // 4140 B
  unsigned*       ovrcnt  = (unsigned*)w;       w += 16;                       // pad
  const size_t need = (size_t)(w - (char*)d_ws);

  if (ws_size >= need) {
    // zero globcur + ovrcnt (one contiguous region)
    hipMemsetAsync(globcur, 0, (size_t)NBUCK * 4 + 16, stream);
    k_scatter_bucket<<<NB_SCAT, NT_SCAT, 0, stream>>>(x, xT2, vp, vb, vw, nv, globcur,
                                                      ovrcnt, ovrlist, sorted);
    k_spmm_static<<<NBUCK, 512, 0, stream>>>(sorted, globcur, xT2, out,
                                             ovrcnt, ovrlist);
  } else {
    hipMemsetAsync(out, 0, (size_t)out_size * sizeof(float), stream);
    ht_fallback<<<256, 1024, 0, stream>>>(x, vp, vb, vw, out, nv);
  }
}

// Round 2
// 141.063 us; speedup vs baseline: 1.2238x; 1.2238x over previous
//
#include <hip/hip_runtime.h>
#include <stdint.h>

// Problem constants
#define IM_HW   16384            // 128*128 pixels
#define NBINS   33120            // 184*180
#define NMAPS   32               // b*c = 2*16
#define INV_NORM (1.0f / 128.0f)

#define BBITS   5                // bins per bucket = 32
#define NBUCK   1035             // NBINS/32 exactly
#define CAPB    4352             // slots/bucket (mean 3865, +7.8 sigma), %4==0
#define SLAB    192              // LDS slots per fine bin (mean 120.8, +6.5 sigma)
#define SSTR    194              // slab stride (even: b64-aligned; ≡2 mod 32: bank spread)
#define NB_SCAT 512              // scatter blocks (2 resident/CU)
#define NT_SCAT 1024             // scatter threads/block
#define LDSVOT  7936             // >= 4-aligned ceil(4e6/512)=7816 block-local votes
#define OVR_CAP 8192             // overflow list capacity (votes)

// Weight encoding: top-13 bits of the f16 bit pattern, stored at [19,32).
__device__ __forceinline__ float w_from_top13(unsigned e) {   // e>>19 = top13
  const unsigned short hb = (unsigned short)((e >> 19) << 3);
  return (float)__builtin_bit_cast(_Float16, hb);
}
__device__ __forceinline__ float f16u(unsigned short h) {
  return (float)__builtin_bit_cast(_Float16, h);
}

// ---------- bucket scatter + fused xT(f16) transpose prologue -----------------
// R10: 512x1024 (2 blocks/CU, 32 waves/CU) + DENSE flush. R9's regression was
// the O(NBUCK) sparse flush (129 bucket-iters/wave, ~8% lane util) + 3x fixed
// overhead. Dense flush is O(votes), 100% lane util, block-count independent:
// a parallel bid[] LDS array maps staged slot i -> bucket, so flush is a flat
// sweep writing g = cur[bu] + i - lstart[bu].
__global__ __launch_bounds__(NT_SCAT) void k_scatter_bucket(
    const float* __restrict__ x, unsigned short* __restrict__ xT2,
    const int* __restrict__ vp, const int* __restrict__ vb,
    const float* __restrict__ vw, int nv,
    unsigned* __restrict__ globcur,      // [NBUCK] bucket fills (pre-zeroed)
    unsigned* __restrict__ ovrcnt,       // [1] overflow count (pre-zeroed)
    uint2*   __restrict__ ovrlist,       // [OVR_CAP]
    unsigned* __restrict__ sorted) {     // [NBUCK*CAPB] 4B entries
  __shared__ unsigned h[NBUCK];          // per-bucket counts
  __shared__ unsigned lstart[NBUCK];     // local exclusive starts
  __shared__ unsigned cur[NBUCK];        // global reserved bases
  __shared__ unsigned lds[LDSVOT];       // block-local bucket-sorted votes (31.0KB)
  __shared__ unsigned short bid[LDSVOT]; // bucket id per staged slot (15.5KB)

  const int tid = threadIdx.x;

  // fused transpose+cvt: x[32][16384] -> xT2[16384][32] f16 (write-coalesced)
  // 524288 elements over 512 blocks = 1024 each (one per thread).
  {
    const int i = blockIdx.x * 1024 + tid;     // i = p*32 + m
    const int m = i & 31, p = i >> 5;
    xT2[i] = __builtin_bit_cast(unsigned short, (_Float16)x[m * IM_HW + p]);
  }

  const int chunk = (((nv + NB_SCAT - 1) / NB_SCAT) + 3) & ~3;   // 4-aligned
  const int c0 = blockIdx.x * chunk;
  const int c1 = min(nv, c0 + chunk);
  const int cnt = (c1 > c0) ? (c1 - c0) : 0;    // <= 7816 <= LDSVOT

  for (int i = tid; i < NBUCK; i += NT_SCAT) h[i] = 0u;
  __syncthreads();

  // stage + rank (1 LDS atomic per vote; return value = within-bucket rank)
  unsigned e[16];
  unsigned short rr[16], bu16[16];
  const int ng = cnt >> 2;                       // groups of 4 votes (<=1954)
  const int4*   vp4 = (const int4*)(vp + c0);
  const int4*   vb4 = (const int4*)(vb + c0);
  const float4* vw4 = (const float4*)(vw + c0);
  #pragma unroll
  for (int j = 0; j < 4; ++j) {
    const int g = tid + j * NT_SCAT;
    if (g < ng) {
      const int4 p = vp4[g]; const int4 b = vb4[g]; const float4 w = vw4[g];
      const int k = j * 4;
      #define STAGE(q, PP, BB, WW) { \
        const unsigned short hw = __builtin_bit_cast(unsigned short, (_Float16)(WW)); \
        e[k + q] = (unsigned)(PP) | (((unsigned)(BB) & 31u) << 14) | (((unsigned)hw >> 3) << 19); \
        bu16[k + q] = (unsigned short)((unsigned)(BB) >> BBITS); \
        rr[k + q] = (unsigned short)atomicAdd(&h[(unsigned)(BB) >> BBITS], 1u); }
      STAGE(0, p.x, b.x, w.x) STAGE(1, p.y, b.y, w.y)
      STAGE(2, p.z, b.z, w.z) STAGE(3, p.w, b.w, w.w)
      #undef STAGE
    }
  }
  // robustness tail (cnt%4, zero for nv=4M): straight to overflow list
  const int tail0 = ng * 4;
  if (tid < cnt - tail0) {
    const int gi = c0 + tail0 + tid;
    unsigned o = atomicAdd(ovrcnt, 1u);
    if (o < OVR_CAP)
      ovrlist[o] = make_uint2((unsigned)vp[gi] | ((unsigned)vb[gi] << 14),
                              __float_as_uint(vw[gi]));
  }
  __syncthreads();

  // single-wave exclusive scan of h -> lstart (wave 0: 17 buckets/lane + shfl)
  if (tid < 64) {
    const int lo = tid * 17, hi = min(NBUCK, lo + 17);   // 64*17=1088 >= 1035
    unsigned s = 0;
    for (int i = lo; i < hi; ++i) s += h[i];
    unsigned inc = s;
    #pragma unroll
    for (int d = 1; d < 64; d <<= 1) {
      const unsigned v = __shfl_up(inc, d);
      if (tid >= d) inc += v;
    }
    unsigned run = inc - s;                               // exclusive base
    for (int i = lo; i < hi; ++i) { lstart[i] = run; run += h[i]; }
  }
  __syncthreads();
  // one global reservation per non-empty bucket
  for (int i = tid; i < NBUCK; i += NT_SCAT)
    cur[i] = (h[i] != 0u) ? atomicAdd(&globcur[i], h[i]) : 0u;
  __syncthreads();

  // place into LDS, bucket-clustered; record bucket id per slot for dense flush
  #pragma unroll
  for (int j = 0; j < 4; ++j) {
    const int g = tid + j * NT_SCAT;
    if (g < ng) {
      #pragma unroll
      for (int q = 0; q < 4; ++q) {
        const int k = j * 4 + q;
        const unsigned pos = lstart[bu16[k]] + (unsigned)rr[k];
        lds[pos] = e[k];
        bid[pos] = bu16[k];
      }
    }
  }
  __syncthreads();

  // DENSE flush: thread i handles staged slot i. 100% lane util, O(votes).
  // Consecutive i within a bucket run -> consecutive global addresses.
  const int staged = ng << 2;
  for (int i = tid; i < staged; i += NT_SCAT) {
    const unsigned E = lds[i];
    const unsigned bu = bid[i];
    const unsigned g = cur[bu] + (unsigned)i - lstart[bu];
    if (g < CAPB) {
      sorted[(size_t)bu * CAPB + g] = E;
    } else {
      unsigned o = atomicAdd(ovrcnt, 1u);
      if (o < OVR_CAP) {
        const unsigned pp  = E & 0x3FFFu;
        const unsigned bin = (bu << BBITS) + ((E >> 14) & 31u);
        ovrlist[o] = make_uint2(pp | (bin << 14), __float_as_uint(w_from_top13(E)));
      }
    }
  }
}

// ---------- per-bucket spmm + fused overflow merge + transposed epilogue ------
// Compute layout: 64 lanes = 8 vote-slots (q) x 8 map-QUADS (mp); one 8B
// gather (uint2 = 4 f16 maps) + 4 fma per vote-lane.
__global__ __launch_bounds__(512) void k_spmm_static(
    const unsigned* __restrict__ sorted, const unsigned* __restrict__ globcur,
    const unsigned short* __restrict__ xT2, float* __restrict__ out,
    unsigned* __restrict__ ovrcnt, uint2* __restrict__ ovrlist) {
  __shared__ unsigned sv[32 * SSTR];       // 24,832 B
  __shared__ unsigned cur[32];
  __shared__ float tile[32][33];           // [bin][map], +1 pad
  const int tid = threadIdx.x;
  const int bu = blockIdx.x;
  const int n = min((int)globcur[bu], CAPB);

  if (tid < 32) cur[tid] = 0u;
  __syncthreads();

  // place: 4 votes per 16B load, 1 LDS atomic + 1 b32 write per vote
  const uint4* src = (const uint4*)(sorted + (size_t)bu * CAPB);  // CAPB%4==0
  const int nq = n >> 2;
  #define PLACE(E) { \
    const unsigned fb = ((E) >> 14) & 31u; \
    const unsigned s = atomicAdd(&cur[fb], 1u); \
    if (s < SLAB) sv[fb * SSTR + s] = (E) & 0xFFF83FFFu; \
    else { \
      unsigned o = atomicAdd(ovrcnt, 1u); \
      if (o < OVR_CAP) \
        ovrlist[o] = make_uint2(((E) & 0x3FFFu) | ((((unsigned)bu << BBITS) + fb) << 14), \
                                __float_as_uint(w_from_top13(E))); } }
  for (int i = tid; i < nq; i += 512) {
    const uint4 q = src[i];
    PLACE(q.x) PLACE(q.y) PLACE(q.z) PLACE(q.w)
  }
  if (tid < (n & 3)) {                     // tail votes (<=3)
    const unsigned E = sorted[(size_t)bu * CAPB + (n & ~3) + tid];
    PLACE(E)
  }
  #undef PLACE
  __syncthreads();

  // compute: wave wv -> bins [wv*4, wv*4+4). Slot q takes votes 2q,2q+1 per
  // 16-vote iter (uint2 pairs); per vote one uint2 load = 4 f16 maps + 4 fma.
  #define WDEC(E) ((float)__builtin_bit_cast(_Float16, (unsigned short)((E) >> 16)))
  const uint2* xh4 = (const uint2*)xT2;    // [16384][8] map-quads
  const int wv = tid >> 6, lane = tid & 63;
  const int q = lane >> 3, mp = lane & 7;
  #pragma unroll
  for (int s4 = 0; s4 < 4; ++s4) {
    const int b = wv * 4 + s4;
    const int cnt = min((int)cur[b], SLAB);
    const unsigned* seg = &sv[b * SSTR];
    float a0 = 0.0f, a1 = 0.0f, a2 = 0.0f, a3 = 0.0f;
    int base = 0;
    for (; base + 16 <= cnt; base += 16) { // 16 votes/iter: slot q -> 2 votes
      const uint2 a = *(const uint2*)(seg + base + 2 * q);
      {
        const uint2 xv = xh4[(a.x & 0x3FFFu) * 8 + mp];
        const float w = WDEC(a.x);
        a0 += w * f16u((unsigned short)(xv.x & 0xFFFFu));
        a1 += w * f16u((unsigned short)(xv.x >> 16));
        a2 += w * f16u((unsigned short)(xv.y & 0xFFFFu));
        a3 += w * f16u((unsigned short)(xv.y >> 16));
      }
      {
        const uint2 xv = xh4[(a.y & 0x3FFFu) * 8 + mp];
        const float w = WDEC(a.y);
        a0 += w * f16u((unsigned short)(xv.x & 0xFFFFu));
        a1 += w * f16u((unsigned short)(xv.x >> 16));
        a2 += w * f16u((unsigned short)(xv.y & 0xFFFFu));
        a3 += w * f16u((unsigned short)(xv.y >> 16));
      }
    }
    for (int j = base + q; j < cnt; j += 8) {    // tail: <=15 votes, stride-8
      const unsigned E = seg[j];
      const uint2 xv = xh4[(E & 0x3FFFu) * 8 + mp];
      const float w = WDEC(E);
      a0 += w * f16u((unsigned short)(xv.x & 0xFFFFu));
      a1 += w * f16u((unsigned short)(xv.x >> 16));
      a2 += w * f16u((unsigned short)(xv.y & 0xFFFFu));
      a3 += w * f16u((unsigned short)(xv.y >> 16));
    }
    // combine the 8 slots (lanes mp, mp+8, ..., mp+56)
    a0 += __shfl_xor(a0, 8); a0 += __shfl_xor(a0, 16); a0 += __shfl_xor(a0, 32);
    a1 += __shfl_xor(a1, 8); a1 += __shfl_xor(a1, 16); a1 += __shfl_xor(a1, 32);
    a2 += __shfl_xor(a2, 8); a2 += __shfl_xor(a2, 16); a2 += __shfl_xor(a2, 32);
    a3 += __shfl_xor(a3, 8); a3 += __shfl_xor(a3, 16); a3 += __shfl_xor(a3, 32);
    if (lane < 8) {
      tile[b][4 * mp]     = a0 * INV_NORM;
      tile[b][4 * mp + 1] = a1 * INV_NORM;
      tile[b][4 * mp + 2] = a2 * INV_NORM;
      tile[b][4 * mp + 3] = a3 * INV_NORM;
    }
  }
  #undef WDEC
  __syncthreads();

  // fused overflow merge: rare entries for THIS bucket -> atomicAdd into tile
  {
    unsigned nov = *ovrcnt;
    nov = nov < (unsigned)OVR_CAP ? nov : (unsigned)OVR_CAP;
    if (nov) {
      for (unsigned idx = tid; idx < nov * 32u; idx += 512u) {
        const unsigned vi = idx >> 5, m2 = idx & 31u;
        const uint2 vv = ovrlist[vi];
        const unsigned bin = vv.x >> 14;
        if ((bin >> BBITS) == (unsigned)bu) {
          const float xv = f16u(xT2[(vv.x & 0x3FFFu) * 32 + m2]);
          atomicAdd(&tile[bin & 31u][m2],
                    __uint_as_float(vv.y) * xv * INV_NORM);
        }
      }
      __syncthreads();
    }
  }

  // fused transposed write: out[m][bin_base + c] for c in [0,32).
  {
    const int row  = tid >> 4;             // 0..31 (map index)
    const int col2 = (tid & 15) * 2;       // 0,2,..,30 (bin offset)
    const int gb0  = bu << BBITS;
    const float2 v2 = make_float2(tile[col2][row], tile[col2 + 1][row]);
    *(float2*)(out + (size_t)row * NBINS + gb0 + col2) = v2;
  }
}

// ---------- fallback (ws too small): R1 LDS-histogram version -----------------
__global__ __launch_bounds__(1024) void ht_fallback(const float* __restrict__ x,
                                                    const int* __restrict__ vp,
                                                    const int* __restrict__ vb,
                                                    const float* __restrict__ vw,
                                                    float* __restrict__ out, int nv) {
  __shared__ float hist[NBINS];
  for (int i = threadIdx.x; i < NBINS; i += 1024) hist[i] = 0.0f;
  __syncthreads();
  const int map = blockIdx.x >> 3, chunk = blockIdx.x & 7;
  const float* xm = x + map * IM_HW;
  const int per = (nv + 7) / 8;
  const int start = chunk * per, end = min(nv, start + per);
  for (int i = start + (int)threadIdx.x; i < end; i += 1024)
    atomicAdd(&hist[vb[i]], xm[vp[i]] * vw[i]);
  __syncthreads();
  float* om = out + map * NBINS;
  for (int i = threadIdx.x; i < NBINS; i += 1024)
    atomicAdd(&om[i], hist[i] * INV_NORM);
}

extern "C" void kernel_launch(void* const* d_in, const int* in_sizes, int n_in,
                              void* d_out, int out_size, void* d_ws, size_t ws_size,
                              hipStream_t stream) {
  const float* x  = (const float*)d_in[0];
  const int*   vp = (const int*)d_in[1];
  const int*   vb = (const int*)d_in[2];
  const float* vw = (const float*)d_in[3];
  float* out = (float*)d_out;
  const int nv = in_sizes[1];

  // ws layout (all sections 16B-aligned)
  char* w = (char*)d_ws;
  unsigned*       sorted  = (unsigned*)w;       w += (size_t)NBUCK * CAPB * 4; // 18.0 MB
  unsigned short* xT2     = (unsigned short*)w; w += (size_t)IM_HW * NMAPS * 2; // 1 MB
  uint2*          ovrlist = (uint2*)w;          w += (size_t)OVR_CAP * 8;      // 64 KB
  unsigned*       globcur = (unsigned*)w;       w += (size_t)NBUCK * 4;        // 4140 B
  unsigned*       ovrcnt  = (unsigned*)w;       w += 16;                       // pad
  const size_t need = (size_t)(w - (char*)d_ws);

  if (ws_size >= need) {
    // zero globcur + ovrcnt (one contiguous region)
    hipMemsetAsync(globcur, 0, (size_t)NBUCK * 4 + 16, stream);
    k_scatter_bucket<<<NB_SCAT, NT_SCAT, 0, stream>>>(x, xT2, vp, vb, vw, nv, globcur,
                                                      ovrcnt, ovrlist, sorted);
    k_spmm_static<<<NBUCK, 512, 0, stream>>>(sorted, globcur, xT2, out,
                                             ovrcnt, ovrlist);
  } else {
    hipMemsetAsync(out, 0, (size_t)out_size * sizeof(float), stream);
    ht_fallback<<<256, 1024, 0, stream>>>(x, vp, vb, vw, out, nv);
  }
}

// Round 3
// 137.110 us; speedup vs baseline: 1.2591x; 1.0288x over previous
//
#include <hip/hip_runtime.h>
#include <stdint.h>

// Problem constants
#define IM_HW   16384            // 128*128 pixels
#define NBINS   33120            // 184*180
#define NMAPS   32               // b*c = 2*16
#define INV_NORM (1.0f / 128.0f)

#define BBITS   5                // bins per bucket = 32
#define NBUCK   1035             // NBINS/32 exactly
#define CAPB    4352             // slots/bucket (mean 3865, +7.8 sigma), %4==0
#define SLAB    192              // LDS slots per fine bin (mean 120.8, +6.5 sigma)
#define SSTR    196              // slab stride (R11: %4==0 -> every slab 16B-aligned for b128)
#define NB_SCAT 512              // scatter blocks (2 resident/CU)
#define NT_SCAT 1024             // scatter threads/block
#define LDSVOT  7936             // >= 4-aligned ceil(4e6/512)=7816 block-local votes
#define OVR_CAP 8192             // overflow list capacity (votes)

// Weight encoding: top-13 bits of the f16 bit pattern, stored at [19,32).
__device__ __forceinline__ float w_from_top13(unsigned e) {   // e>>19 = top13
  const unsigned short hb = (unsigned short)((e >> 19) << 3);
  return (float)__builtin_bit_cast(_Float16, hb);
}
__device__ __forceinline__ float f16u(unsigned short h) {
  return (float)__builtin_bit_cast(_Float16, h);
}

// ---------- bucket scatter + fused xT(f16) transpose prologue -----------------
// R10: 512x1024 (2 blocks/CU) + dense O(votes) flush.
// R11: scan (wave 0) and global reservation (waves 1-15) run CONCURRENTLY in
// one phase (reserve needs only h[], not lstart[]) -- one fewer barrier and the
// ~700cyc global-atomic latency hides under the scan. Flush does 2 votes/thread.
__global__ __launch_bounds__(NT_SCAT) void k_scatter_bucket(
    const float* __restrict__ x, unsigned short* __restrict__ xT2,
    const int* __restrict__ vp, const int* __restrict__ vb,
    const float* __restrict__ vw, int nv,
    unsigned* __restrict__ globcur,      // [NBUCK] bucket fills (pre-zeroed)
    unsigned* __restrict__ ovrcnt,       // [1] overflow count (pre-zeroed)
    uint2*   __restrict__ ovrlist,       // [OVR_CAP]
    unsigned* __restrict__ sorted) {     // [NBUCK*CAPB] 4B entries
  __shared__ unsigned h[NBUCK];          // per-bucket counts
  __shared__ unsigned lstart[NBUCK];     // local exclusive starts
  __shared__ unsigned cur[NBUCK];        // global reserved bases
  __shared__ unsigned lds[LDSVOT];       // block-local bucket-sorted votes (31.0KB)
  __shared__ unsigned short bid[LDSVOT]; // bucket id per staged slot (15.5KB)

  const int tid = threadIdx.x;

  // fused transpose+cvt: x[32][16384] -> xT2[16384][32] f16 (write-coalesced)
  // 524288 elements over 512 blocks = 1024 each (one per thread).
  {
    const int i = blockIdx.x * 1024 + tid;     // i = p*32 + m
    const int m = i & 31, p = i >> 5;
    xT2[i] = __builtin_bit_cast(unsigned short, (_Float16)x[m * IM_HW + p]);
  }

  const int chunk = (((nv + NB_SCAT - 1) / NB_SCAT) + 3) & ~3;   // 4-aligned
  const int c0 = blockIdx.x * chunk;
  const int c1 = min(nv, c0 + chunk);
  const int cnt = (c1 > c0) ? (c1 - c0) : 0;    // <= 7816 <= LDSVOT

  for (int i = tid; i < NBUCK; i += NT_SCAT) h[i] = 0u;
  __syncthreads();

  // stage + rank (1 LDS atomic per vote; return value = within-bucket rank)
  unsigned e[16];
  unsigned short rr[16], bu16[16];
  const int ng = cnt >> 2;                       // groups of 4 votes (<=1954)
  const int4*   vp4 = (const int4*)(vp + c0);
  const int4*   vb4 = (const int4*)(vb + c0);
  const float4* vw4 = (const float4*)(vw + c0);
  #pragma unroll
  for (int j = 0; j < 4; ++j) {
    const int g = tid + j * NT_SCAT;
    if (g < ng) {
      const int4 p = vp4[g]; const int4 b = vb4[g]; const float4 w = vw4[g];
      const int k = j * 4;
      #define STAGE(q, PP, BB, WW) { \
        const unsigned short hw = __builtin_bit_cast(unsigned short, (_Float16)(WW)); \
        e[k + q] = (unsigned)(PP) | (((unsigned)(BB) & 31u) << 14) | (((unsigned)hw >> 3) << 19); \
        bu16[k + q] = (unsigned short)((unsigned)(BB) >> BBITS); \
        rr[k + q] = (unsigned short)atomicAdd(&h[(unsigned)(BB) >> BBITS], 1u); }
      STAGE(0, p.x, b.x, w.x) STAGE(1, p.y, b.y, w.y)
      STAGE(2, p.z, b.z, w.z) STAGE(3, p.w, b.w, w.w)
      #undef STAGE
    }
  }
  // robustness tail (cnt%4, zero for nv=4M): straight to overflow list
  const int tail0 = ng * 4;
  if (tid < cnt - tail0) {
    const int gi = c0 + tail0 + tid;
    unsigned o = atomicAdd(ovrcnt, 1u);
    if (o < OVR_CAP)
      ovrlist[o] = make_uint2((unsigned)vp[gi] | ((unsigned)vb[gi] << 14),
                              __float_as_uint(vw[gi]));
  }
  __syncthreads();

  // CONCURRENT: wave 0 scans h -> lstart; waves 1-15 reserve global bases.
  if (tid < 64) {
    const int lo = tid * 17, hi = min(NBUCK, lo + 17);   // 64*17=1088 >= 1035
    unsigned s = 0;
    for (int i = lo; i < hi; ++i) s += h[i];
    unsigned inc = s;
    #pragma unroll
    for (int d = 1; d < 64; d <<= 1) {
      const unsigned v = __shfl_up(inc, d);
      if (tid >= d) inc += v;
    }
    unsigned run = inc - s;                               // exclusive base
    for (int i = lo; i < hi; ++i) { lstart[i] = run; run += h[i]; }
  } else {
    // 960 threads cover all NBUCK reservations (needs only h[], done at barrier)
    for (int i = tid - 64; i < NBUCK; i += (NT_SCAT - 64))
      cur[i] = (h[i] != 0u) ? atomicAdd(&globcur[i], h[i]) : 0u;
  }
  __syncthreads();

  // place into LDS, bucket-clustered; record bucket id per slot for dense flush
  #pragma unroll
  for (int j = 0; j < 4; ++j) {
    const int g = tid + j * NT_SCAT;
    if (g < ng) {
      #pragma unroll
      for (int q = 0; q < 4; ++q) {
        const int k = j * 4 + q;
        const unsigned pos = lstart[bu16[k]] + (unsigned)rr[k];
        lds[pos] = e[k];
        bid[pos] = bu16[k];
      }
    }
  }
  __syncthreads();

  // DENSE flush, 2 votes/thread: slot i even -> uint2 LDS read (8B aligned),
  // bid pair as one 4B read. 100% lane util, O(votes).
  const int staged = ng << 2;                  // multiple of 4
  for (int i = (tid << 1); i < staged; i += (NT_SCAT << 1)) {
    const uint2 E2 = *(const uint2*)&lds[i];
    const unsigned bp = *(const unsigned*)&bid[i];
    const unsigned b0 = bp & 0xFFFFu, b1 = bp >> 16;
    const unsigned g0 = cur[b0] + (unsigned)i       - lstart[b0];
    const unsigned g1 = cur[b1] + (unsigned)(i + 1) - lstart[b1];
    if (g0 < CAPB) {
      sorted[(size_t)b0 * CAPB + g0] = E2.x;
    } else {
      unsigned o = atomicAdd(ovrcnt, 1u);
      if (o < OVR_CAP) {
        const unsigned bin = (b0 << BBITS) + ((E2.x >> 14) & 31u);
        ovrlist[o] = make_uint2((E2.x & 0x3FFFu) | (bin << 14),
                                __float_as_uint(w_from_top13(E2.x)));
      }
    }
    if (g1 < CAPB) {
      sorted[(size_t)b1 * CAPB + g1] = E2.y;
    } else {
      unsigned o = atomicAdd(ovrcnt, 1u);
      if (o < OVR_CAP) {
        const unsigned bin = (b1 << BBITS) + ((E2.y >> 14) & 31u);
        ovrlist[o] = make_uint2((E2.y & 0x3FFFu) | (bin << 14),
                                __float_as_uint(w_from_top13(E2.y)));
      }
    }
  }
}

// ---------- per-bucket spmm + fused overflow merge + transposed epilogue ------
// Compute layout: 64 lanes = 8 vote-slots (q) x 8 map-QUADS (mp); one 8B
// gather (uint2 = 4 f16 maps) + 4 fma per vote-lane.
// R11: 32-vote main iter (uint4 slab read -> 4 independent gathers/lane in
// flight) + ovrcnt load issued BEFORE compute (latency hides under ~6us VALU).
__global__ __launch_bounds__(512) void k_spmm_static(
    const unsigned* __restrict__ sorted, const unsigned* __restrict__ globcur,
    const unsigned short* __restrict__ xT2, float* __restrict__ out,
    unsigned* __restrict__ ovrcnt, uint2* __restrict__ ovrlist) {
  __shared__ unsigned sv[32 * SSTR];       // 25,088 B (16B-aligned slabs)
  __shared__ unsigned cur[32];
  __shared__ float tile[32][33];           // [bin][map], +1 pad
  const int tid = threadIdx.x;
  const int bu = blockIdx.x;
  const int n = min((int)globcur[bu], CAPB);

  if (tid < 32) cur[tid] = 0u;
  __syncthreads();

  // place: 4 votes per 16B load, 1 LDS atomic + 1 b32 write per vote
  const uint4* src = (const uint4*)(sorted + (size_t)bu * CAPB);  // CAPB%4==0
  const int nq = n >> 2;
  #define PLACE(E) { \
    const unsigned fb = ((E) >> 14) & 31u; \
    const unsigned s = atomicAdd(&cur[fb], 1u); \
    if (s < SLAB) sv[fb * SSTR + s] = (E) & 0xFFF83FFFu; \
    else { \
      unsigned o = atomicAdd(ovrcnt, 1u); \
      if (o < OVR_CAP) \
        ovrlist[o] = make_uint2(((E) & 0x3FFFu) | ((((unsigned)bu << BBITS) + fb) << 14), \
                                __float_as_uint(w_from_top13(E))); } }
  for (int i = tid; i < nq; i += 512) {
    const uint4 q = src[i];
    PLACE(q.x) PLACE(q.y) PLACE(q.z) PLACE(q.w)
  }
  if (tid < (n & 3)) {                     // tail votes (<=3)
    const unsigned E = sorted[(size_t)bu * CAPB + (n & ~3) + tid];
    PLACE(E)
  }
  #undef PLACE
  __syncthreads();

  // issue the overflow-count load now; consumed after compute (latency hidden).
  // Own block's place-overflows are visible (device atomic + __syncthreads);
  // other blocks' concurrent entries belong to other buckets.
  unsigned nov = *ovrcnt;

  // compute: wave wv -> bins [wv*4, wv*4+4).
  #define WDEC(E) ((float)__builtin_bit_cast(_Float16, (unsigned short)((E) >> 16)))
  #define PROC(E) { \
    const uint2 xv = xh4[((E) & 0x3FFFu) * 8 + mp]; \
    const float w = WDEC(E); \
    a0 += w * f16u((unsigned short)(xv.x & 0xFFFFu)); \
    a1 += w * f16u((unsigned short)(xv.x >> 16)); \
    a2 += w * f16u((unsigned short)(xv.y & 0xFFFFu)); \
    a3 += w * f16u((unsigned short)(xv.y >> 16)); }
  const uint2* xh4 = (const uint2*)xT2;    // [16384][8] map-quads
  const int wv = tid >> 6, lane = tid & 63;
  const int q = lane >> 3, mp = lane & 7;
  #pragma unroll
  for (int s4 = 0; s4 < 4; ++s4) {
    const int b = wv * 4 + s4;
    const int cnt = min((int)cur[b], SLAB);
    const unsigned* seg = &sv[b * SSTR];
    float a0 = 0.0f, a1 = 0.0f, a2 = 0.0f, a3 = 0.0f;
    int base = 0;
    for (; base + 32 <= cnt; base += 32) { // 32 votes/iter: slot q -> 4 votes
      const uint4 a = *(const uint4*)(seg + base + 4 * q);   // 16B aligned
      PROC(a.x) PROC(a.y) PROC(a.z) PROC(a.w)
    }
    for (int j = base + q; j < cnt; j += 8) {    // tail: <=31 votes, stride-8
      const unsigned E = seg[j];
      PROC(E)
    }
    // combine the 8 slots (lanes mp, mp+8, ..., mp+56)
    a0 += __shfl_xor(a0, 8); a0 += __shfl_xor(a0, 16); a0 += __shfl_xor(a0, 32);
    a1 += __shfl_xor(a1, 8); a1 += __shfl_xor(a1, 16); a1 += __shfl_xor(a1, 32);
    a2 += __shfl_xor(a2, 8); a2 += __shfl_xor(a2, 16); a2 += __shfl_xor(a2, 32);
    a3 += __shfl_xor(a3, 8); a3 += __shfl_xor(a3, 16); a3 += __shfl_xor(a3, 32);
    if (lane < 8) {
      tile[b][4 * mp]     = a0 * INV_NORM;
      tile[b][4 * mp + 1] = a1 * INV_NORM;
      tile[b][4 * mp + 2] = a2 * INV_NORM;
      tile[b][4 * mp + 3] = a3 * INV_NORM;
    }
  }
  #undef PROC
  #undef WDEC
  __syncthreads();

  // fused overflow merge: rare entries for THIS bucket -> atomicAdd into tile
  {
    nov = nov < (unsigned)OVR_CAP ? nov : (unsigned)OVR_CAP;
    if (nov) {
      for (unsigned idx = tid; idx < nov * 32u; idx += 512u) {
        const unsigned vi = idx >> 5, m2 = idx & 31u;
        const uint2 vv = ovrlist[vi];
        const unsigned bin = vv.x >> 14;
        if ((bin >> BBITS) == (unsigned)bu) {
          const float xv = f16u(xT2[(vv.x & 0x3FFFu) * 32 + m2]);
          atomicAdd(&tile[bin & 31u][m2],
                    __uint_as_float(vv.y) * xv * INV_NORM);
        }
      }
      __syncthreads();
    }
  }

  // fused transposed write: out[m][bin_base + c] for c in [0,32).
  {
    const int row  = tid >> 4;             // 0..31 (map index)
    const int col2 = (tid & 15) * 2;       // 0,2,..,30 (bin offset)
    const int gb0  = bu << BBITS;
    const float2 v2 = make_float2(tile[col2][row], tile[col2 + 1][row]);
    *(float2*)(out + (size_t)row * NBINS + gb0 + col2) = v2;
  }
}

// ---------- fallback (ws too small): R1 LDS-histogram version -----------------
__global__ __launch_bounds__(1024) void ht_fallback(const float* __restrict__ x,
                                                    const int* __restrict__ vp,
                                                    const int* __restrict__ vb,
                                                    const float* __restrict__ vw,
                                                    float* __restrict__ out, int nv) {
  __shared__ float hist[NBINS];
  for (int i = threadIdx.x; i < NBINS; i += 1024) hist[i] = 0.0f;
  __syncthreads();
  const int map = blockIdx.x >> 3, chunk = blockIdx.x & 7;
  const float* xm = x + map * IM_HW;
  const int per = (nv + 7) / 8;
  const int start = chunk * per, end = min(nv, start + per);
  for (int i = start + (int)threadIdx.x; i < end; i += 1024)
    atomicAdd(&hist[vb[i]], xm[vp[i]] * vw[i]);
  __syncthreads();
  float* om = out + map * NBINS;
  for (int i = threadIdx.x; i < NBINS; i += 1024)
    atomicAdd(&om[i], hist[i] * INV_NORM);
}

extern "C" void kernel_launch(void* const* d_in, const int* in_sizes, int n_in,
                              void* d_out, int out_size, void* d_ws, size_t ws_size,
                              hipStream_t stream) {
  const float* x  = (const float*)d_in[0];
  const int*   vp = (const int*)d_in[1];
  const int*   vb = (const int*)d_in[2];
  const float* vw = (const float*)d_in[3];
  float* out = (float*)d_out;
  const int nv = in_sizes[1];

  // ws layout (all sections 16B-aligned)
  char* w = (char*)d_ws;
  unsigned*       sorted  = (unsigned*)w;       w += (size_t)NBUCK * CAPB * 4; // 18.0 MB
  unsigned short* xT2     = (unsigned short*)w; w += (size_t)IM_HW * NMAPS * 2; // 1 MB
  uint2*          ovrlist = (uint2*)w;          w += (size_t)OVR_CAP * 8;      // 64 KB
  unsigned*       globcur = (unsigned*)w;       w += (size_t)NBUCK * 4;        // 4140 B
  unsigned*       ovrcnt  = (unsigned*)w;       w += 16;                       // pad
  const size_t need = (size_t)(w - (char*)d_ws);

  if (ws_size >= need) {
    // zero globcur + ovrcnt (one contiguous region)
    hipMemsetAsync(globcur, 0, (size_t)NBUCK * 4 + 16, stream);
    k_scatter_bucket<<<NB_SCAT, NT_SCAT, 0, stream>>>(x, xT2, vp, vb, vw, nv, globcur,
                                                      ovrcnt, ovrlist, sorted);
    k_spmm_static<<<NBUCK, 512, 0, stream>>>(sorted, globcur, xT2, out,
                                             ovrcnt, ovrlist);
  } else {
    hipMemsetAsync(out, 0, (size_t)out_size * sizeof(float), stream);
    ht_fallback<<<256, 1024, 0, stream>>>(x, vp, vb, vw, out, nv);
  }
}